// Round 1
// baseline (71.817 us; speedup 1.0000x reference)
//
#include <hip/hip_runtime.h>

// Grouped conv: x (1,48,56,56) f32, w (24,96,7) f32, groups=2.
// kernel[o,i,0,k] = w[i, o%96, k];  group g = o/96 uses in-chans [24g,24g+24).
// y[o,h,wo] = sum_{i<24,k<7} x[24g+i, h, wo+k-3] * w[i, o%96, k]   (pad 3 on W)
// out[o,h,:] = y[o, (h - shift) mod 56, :]   (jnp.roll along H)

#define H 56
#define W 56
#define C_GRP 24
#define KW 7
#define HW (H * W)

__global__ __launch_bounds__(64) void conv7_roll_kernel(
    const float* __restrict__ x,
    const float* __restrict__ w,
    const int* __restrict__ shift_p,
    float* __restrict__ out)
{
    const int o     = blockIdx.x;      // 0..191 output channel
    const int htile = blockIdx.y;      // 0..6
    const int lane  = threadIdx.x;     // 0..63
    const int r     = lane >> 3;       // 0..7  (row within tile)
    const int s     = lane & 7;        // 0..7  (strip of 7 cols)
    const int h_out = htile * 8 + r;
    const int wbase = s * 7;

    const int g  = o / 96;
    const int oc = o % 96;

    // Stage weights for this output channel: wl[i*7+k] = w[i, oc, k]
    __shared__ float wl[C_GRP * KW];
    for (int t = lane; t < C_GRP * KW; t += 64) {
        const int i = t / 7;
        const int k = t - i * 7;
        wl[t] = w[i * (96 * 7) + oc * 7 + k];
    }
    __syncthreads();

    const int shift = shift_p[0];
    int hi = (h_out - shift) % H;
    if (hi < 0) hi += H;

    float acc[7] = {0.f, 0.f, 0.f, 0.f, 0.f, 0.f, 0.f};

    const float* xg = x + (g * C_GRP) * HW + hi * W;

    for (int i = 0; i < C_GRP; ++i) {
        const float* xr = xg + i * HW;
        // 13-wide window covering outputs [wbase, wbase+7) with taps [-3,+3]
        float xv[13];
        #pragma unroll
        for (int j = 0; j < 13; ++j) {
            const int p = wbase - 3 + j;
            xv[j] = (p >= 0 && p < W) ? xr[p] : 0.0f;
        }
        #pragma unroll
        for (int k = 0; k < KW; ++k) {
            const float wk = wl[i * KW + k];
            #pragma unroll
            for (int j = 0; j < 7; ++j)
                acc[j] += xv[j + k] * wk;
        }
    }

    float* op = out + o * HW + h_out * W + wbase;
    #pragma unroll
    for (int j = 0; j < 7; ++j)
        op[j] = acc[j];
}

extern "C" void kernel_launch(void* const* d_in, const int* in_sizes, int n_in,
                              void* d_out, int out_size, void* d_ws, size_t ws_size,
                              hipStream_t stream)
{
    const float* x     = (const float*)d_in[0];
    const float* w     = (const float*)d_in[1];
    const int*   shift = (const int*)d_in[2];
    float*       out   = (float*)d_out;

    dim3 grid(192, 7);
    conv7_roll_kernel<<<grid, 64, 0, stream>>>(x, w, shift, out);
}